// Round 3
// baseline (31.225 us; speedup 1.0000x reference)
//
#include <hip/hip_runtime.h>
#include <hip/hip_bf16.h>

// 3D inverse Haar wavelet recombination.
// Input  x : (B=2, 8*C=256, D=32, H=32, W=32) fp32, band index = 4i+2j+k in
//            the high bits of the channel dim (c8 = band*32 + c).
// Output   : (B=2, C=32, 2D=64, 2H=64, 2W=64) fp32,
//            out[b,c,2d+p,2h+q,2w+r] = sum_{ijk} (-1)^(ip+jq+kr) x[b,(4i+2j+k)*C+c,d,h,w]
//
// R3: 4 coarse w-voxels per thread; nontemporal float4 via clang ext_vector
// (HIP_vector_type structs are rejected by the nontemporal builtins).
//   loads  : 8 bands x 16 B/lane, nontemporal (streaming, no reuse)
//   stores : 8 x 16 B, nontemporal
// Butterfly is separable: 3 stages x 8 adds per voxel.

typedef float f32x4 __attribute__((ext_vector_type(4)));

#define C_DIM   32
#define D_DIM   32
#define H_DIM   32
#define W_DIM   32
#define W4      (W_DIM / 4)                 // 8 w-quads
#define SPATIAL (D_DIM * H_DIM * W_DIM)     // 32768
#define BAND_STRIDE (C_DIM * SPATIAL)       // 1048576 floats between bands
#define OUT_CH_STRIDE (8 * SPATIAL)         // 64*64*64 = 262144

__global__ __launch_bounds__(256) void iwt3d_kernel(const float* __restrict__ x,
                                                    float* __restrict__ out) {
    int t = blockIdx.x * blockDim.x + threadIdx.x;
    // total threads = B * C * D * H * W4 = 2*32*32*32*8 = 524,288

    int w4 = t & (W4 - 1);        int r = t >> 3;
    int h  = r & (H_DIM - 1);     r >>= 5;
    int d  = r & (D_DIM - 1);     r >>= 5;
    int c  = r & (C_DIM - 1);     r >>= 5;
    int b  = r;                   // 0..1

    size_t in_base = (size_t)b * (8 * BAND_STRIDE)
                   + (size_t)c * SPATIAL
                   + (size_t)d * (H_DIM * W_DIM)
                   + (size_t)h * W_DIM
                   + (size_t)(w4 * 4);

    // v[band][e] : band = 4i+2j+k, e = which of the 4 voxels
    float v[8][4];
#pragma unroll
    for (int s = 0; s < 8; ++s) {
        f32x4 ld = __builtin_nontemporal_load(
            reinterpret_cast<const f32x4*>(x + in_base + (size_t)s * BAND_STRIDE));
        v[s][0] = ld.x; v[s][1] = ld.y; v[s][2] = ld.z; v[s][3] = ld.w;
    }

    // Stage 1 (over k -> r): tk[4i+2j+r]
    float tk[8][4];
#pragma unroll
    for (int ij = 0; ij < 4; ++ij) {
#pragma unroll
        for (int e = 0; e < 4; ++e) {
            tk[ij * 2 + 0][e] = v[ij * 2 + 0][e] + v[ij * 2 + 1][e];
            tk[ij * 2 + 1][e] = v[ij * 2 + 0][e] - v[ij * 2 + 1][e];
        }
    }

    // Stage 2 (over j -> q): uq[4i+2q+r]
    float uq[8][4];
#pragma unroll
    for (int i = 0; i < 2; ++i) {
#pragma unroll
        for (int rr = 0; rr < 2; ++rr) {
#pragma unroll
            for (int e = 0; e < 4; ++e) {
                uq[i * 4 + 0 + rr][e] = tk[i * 4 + rr][e] + tk[i * 4 + 2 + rr][e];
                uq[i * 4 + 2 + rr][e] = tk[i * 4 + rr][e] - tk[i * 4 + 2 + rr][e];
            }
        }
    }

    // Stage 3 (over i -> p): o[4p+2q+r]
    float o[8][4];
#pragma unroll
    for (int qr = 0; qr < 4; ++qr) {
#pragma unroll
        for (int e = 0; e < 4; ++e) {
            o[0 + qr][e] = uq[qr][e] + uq[4 + qr][e];
            o[4 + qr][e] = uq[qr][e] - uq[4 + qr][e];
        }
    }

    // Output: out[b, c, 2d+p, 2h+q, 8*w4 + 2e + r], two float4 per (p,q)
    size_t out_cbase = ((size_t)(b * C_DIM + c)) * OUT_CH_STRIDE;
#pragma unroll
    for (int p = 0; p < 2; ++p) {
#pragma unroll
        for (int q = 0; q < 2; ++q) {
            size_t off = out_cbase
                       + (size_t)(2 * d + p) * (2 * H_DIM * 2 * W_DIM)
                       + (size_t)(2 * h + q) * (2 * W_DIM)
                       + (size_t)(8 * w4);
            int pq = p * 4 + q * 2;
            f32x4 s0, s1;
            s0.x = o[pq + 0][0];  // e=0, r=0
            s0.y = o[pq + 1][0];  // e=0, r=1
            s0.z = o[pq + 0][1];  // e=1, r=0
            s0.w = o[pq + 1][1];  // e=1, r=1
            s1.x = o[pq + 0][2];  // e=2, r=0
            s1.y = o[pq + 1][2];  // e=2, r=1
            s1.z = o[pq + 0][3];  // e=3, r=0
            s1.w = o[pq + 1][3];  // e=3, r=1
            __builtin_nontemporal_store(s0, reinterpret_cast<f32x4*>(out + off));
            __builtin_nontemporal_store(s1, reinterpret_cast<f32x4*>(out + off + 4));
        }
    }
}

extern "C" void kernel_launch(void* const* d_in, const int* in_sizes, int n_in,
                              void* d_out, int out_size, void* d_ws, size_t ws_size,
                              hipStream_t stream) {
    const float* x = (const float*)d_in[0];
    float* out = (float*)d_out;

    // B*C*D*H*W4 = 2*32*32*32*8 = 524,288 threads
    const int total = 2 * C_DIM * D_DIM * H_DIM * W4;
    const int block = 256;
    const int grid = total / block;  // 2048
    iwt3d_kernel<<<grid, block, 0, stream>>>(x, out);
}

// Round 4
// 30.720 us; speedup vs baseline: 1.0164x; 1.0164x over previous
//
#include <hip/hip_runtime.h>
#include <hip/hip_bf16.h>

// 3D inverse Haar wavelet recombination.
// Input  x : (B=2, 8*C=256, D=32, H=32, W=32) fp32, band index = 4i+2j+k in
//            the high bits of the channel dim (c8 = band*32 + c).
// Output   : (B=2, C=32, 2D=64, 2H=64, 2W=64) fp32,
//            out[b,c,2d+p,2h+q,2w+r] = sum_{ijk} (-1)^(ip+jq+kr) x[b,(4i+2j+k)*C+c,d,h,w]
//
// R4: 4 coarse w-voxels per thread, PLAIN (temporal) float4 loads/stores.
// R3's nontemporal hint regressed 28.9->31.2 us: the 128 MB total footprint
// fits in the 256 MB Infinity Cache across graph replays, and nt bypassed it.
//   loads  : 8 bands x 16 B/lane (coalesced streams, L3-cacheable)
//   stores : 8 x 16 B (coalesced)
// Butterfly is separable: 3 stages x 8 adds per voxel.

typedef float f32x4 __attribute__((ext_vector_type(4)));

#define C_DIM   32
#define D_DIM   32
#define H_DIM   32
#define W_DIM   32
#define W4      (W_DIM / 4)                 // 8 w-quads
#define SPATIAL (D_DIM * H_DIM * W_DIM)     // 32768
#define BAND_STRIDE (C_DIM * SPATIAL)       // 1048576 floats between bands
#define OUT_CH_STRIDE (8 * SPATIAL)         // 64*64*64 = 262144

__global__ __launch_bounds__(256) void iwt3d_kernel(const float* __restrict__ x,
                                                    float* __restrict__ out) {
    int t = blockIdx.x * blockDim.x + threadIdx.x;
    // total threads = B * C * D * H * W4 = 2*32*32*32*8 = 524,288

    int w4 = t & (W4 - 1);        int r = t >> 3;
    int h  = r & (H_DIM - 1);     r >>= 5;
    int d  = r & (D_DIM - 1);     r >>= 5;
    int c  = r & (C_DIM - 1);     r >>= 5;
    int b  = r;                   // 0..1

    size_t in_base = (size_t)b * (8 * BAND_STRIDE)
                   + (size_t)c * SPATIAL
                   + (size_t)d * (H_DIM * W_DIM)
                   + (size_t)h * W_DIM
                   + (size_t)(w4 * 4);

    // v[band][e] : band = 4i+2j+k, e = which of the 4 voxels
    float v[8][4];
#pragma unroll
    for (int s = 0; s < 8; ++s) {
        f32x4 ld = *reinterpret_cast<const f32x4*>(x + in_base + (size_t)s * BAND_STRIDE);
        v[s][0] = ld.x; v[s][1] = ld.y; v[s][2] = ld.z; v[s][3] = ld.w;
    }

    // Stage 1 (over k -> r): tk[4i+2j+r]
    float tk[8][4];
#pragma unroll
    for (int ij = 0; ij < 4; ++ij) {
#pragma unroll
        for (int e = 0; e < 4; ++e) {
            tk[ij * 2 + 0][e] = v[ij * 2 + 0][e] + v[ij * 2 + 1][e];
            tk[ij * 2 + 1][e] = v[ij * 2 + 0][e] - v[ij * 2 + 1][e];
        }
    }

    // Stage 2 (over j -> q): uq[4i+2q+r]
    float uq[8][4];
#pragma unroll
    for (int i = 0; i < 2; ++i) {
#pragma unroll
        for (int rr = 0; rr < 2; ++rr) {
#pragma unroll
            for (int e = 0; e < 4; ++e) {
                uq[i * 4 + 0 + rr][e] = tk[i * 4 + rr][e] + tk[i * 4 + 2 + rr][e];
                uq[i * 4 + 2 + rr][e] = tk[i * 4 + rr][e] - tk[i * 4 + 2 + rr][e];
            }
        }
    }

    // Stage 3 (over i -> p): o[4p+2q+r]
    float o[8][4];
#pragma unroll
    for (int qr = 0; qr < 4; ++qr) {
#pragma unroll
        for (int e = 0; e < 4; ++e) {
            o[0 + qr][e] = uq[qr][e] + uq[4 + qr][e];
            o[4 + qr][e] = uq[qr][e] - uq[4 + qr][e];
        }
    }

    // Output: out[b, c, 2d+p, 2h+q, 8*w4 + 2e + r], two float4 per (p,q)
    size_t out_cbase = ((size_t)(b * C_DIM + c)) * OUT_CH_STRIDE;
#pragma unroll
    for (int p = 0; p < 2; ++p) {
#pragma unroll
        for (int q = 0; q < 2; ++q) {
            size_t off = out_cbase
                       + (size_t)(2 * d + p) * (2 * H_DIM * 2 * W_DIM)
                       + (size_t)(2 * h + q) * (2 * W_DIM)
                       + (size_t)(8 * w4);
            int pq = p * 4 + q * 2;
            f32x4 s0, s1;
            s0.x = o[pq + 0][0];  // e=0, r=0
            s0.y = o[pq + 1][0];  // e=0, r=1
            s0.z = o[pq + 0][1];  // e=1, r=0
            s0.w = o[pq + 1][1];  // e=1, r=1
            s1.x = o[pq + 0][2];  // e=2, r=0
            s1.y = o[pq + 1][2];  // e=2, r=1
            s1.z = o[pq + 0][3];  // e=3, r=0
            s1.w = o[pq + 1][3];  // e=3, r=1
            *reinterpret_cast<f32x4*>(out + off)     = s0;
            *reinterpret_cast<f32x4*>(out + off + 4) = s1;
        }
    }
}

extern "C" void kernel_launch(void* const* d_in, const int* in_sizes, int n_in,
                              void* d_out, int out_size, void* d_ws, size_t ws_size,
                              hipStream_t stream) {
    const float* x = (const float*)d_in[0];
    float* out = (float*)d_out;

    // B*C*D*H*W4 = 2*32*32*32*8 = 524,288 threads
    const int total = 2 * C_DIM * D_DIM * H_DIM * W4;
    const int block = 256;
    const int grid = total / block;  // 2048
    iwt3d_kernel<<<grid, block, 0, stream>>>(x, out);
}

// Round 5
// 25.703 us; speedup vs baseline: 1.2148x; 1.1952x over previous
//
#include <hip/hip_runtime.h>
#include <hip/hip_bf16.h>

// 3D inverse Haar wavelet recombination.
// Input  x : (B=2, 8*C=256, D=32, H=32, W=32) fp32, band index = 4i+2j+k in
//            the high bits of the channel dim (c8 = band*32 + c).
// Output   : (B=2, C=32, 2D=64, 2H=64, 2W=64) fp32,
//            out[b,c,2d+p,2h+q,2w+r] = sum_{ijk} (-1)^(ip+jq+kr) x[b,(4i+2j+k)*C+c,d,h,w]
//
// R5: back to R1's ownership (2 coarse w per thread) — the unique
// exchange-free mapping with fully dense 16 B stores (R4's 4-voxel variant
// stored 16B-at-32B-stride, 2x write requests/line -> +6%). Loads are 8 B
// dense (full-wave 512 B contiguous per band). Block raised 256 -> 1024 so
// each block covers 8 KB contiguous per band read stream and 32 KB output
// regions (fewer, longer HBM streams).
//   loads  : 8 bands x float2 (512 B/wave-instr, contiguous)
//   stores : 4 x float4       (256 B per 16-lane group, fully dense)

typedef float f32x4 __attribute__((ext_vector_type(4)));

#define C_DIM   32
#define D_DIM   32
#define H_DIM   32
#define W_DIM   32
#define W2      (W_DIM / 2)                 // 16 w-pairs
#define SPATIAL (D_DIM * H_DIM * W_DIM)     // 32768
#define BAND_STRIDE (C_DIM * SPATIAL)       // 1048576 floats between bands
#define OUT_CH_STRIDE (8 * SPATIAL)         // 64*64*64 = 262144

__global__ __launch_bounds__(1024) void iwt3d_kernel(const float* __restrict__ x,
                                                     float* __restrict__ out) {
    int t = blockIdx.x * blockDim.x + threadIdx.x;
    // total threads = B * C * D * H * W2 = 2*32*32*32*16 = 1,048,576

    int w2 = t & (W2 - 1);        int r = t >> 4;
    int h  = r & (H_DIM - 1);     r >>= 5;
    int d  = r & (D_DIM - 1);     r >>= 5;
    int c  = r & (C_DIM - 1);     r >>= 5;
    int b  = r;                   // 0..1

    size_t in_base = (size_t)b * (8 * BAND_STRIDE)
                   + (size_t)c * SPATIAL
                   + (size_t)d * (H_DIM * W_DIM)
                   + (size_t)h * W_DIM
                   + (size_t)(w2 * 2);

    // v[band][e] : band = 4i+2j+k, e = which of the 2 voxels
    float v[8][2];
#pragma unroll
    for (int s = 0; s < 8; ++s) {
        float2 ld = *reinterpret_cast<const float2*>(x + in_base + (size_t)s * BAND_STRIDE);
        v[s][0] = ld.x;
        v[s][1] = ld.y;
    }

    // Stage 1 (over k -> r): tk[4i+2j+r]
    float tk[8][2];
#pragma unroll
    for (int ij = 0; ij < 4; ++ij) {
#pragma unroll
        for (int e = 0; e < 2; ++e) {
            tk[ij * 2 + 0][e] = v[ij * 2 + 0][e] + v[ij * 2 + 1][e];
            tk[ij * 2 + 1][e] = v[ij * 2 + 0][e] - v[ij * 2 + 1][e];
        }
    }

    // Stage 2 (over j -> q): uq[4i+2q+r]
    float uq[8][2];
#pragma unroll
    for (int i = 0; i < 2; ++i) {
#pragma unroll
        for (int rr = 0; rr < 2; ++rr) {
#pragma unroll
            for (int e = 0; e < 2; ++e) {
                uq[i * 4 + 0 + rr][e] = tk[i * 4 + rr][e] + tk[i * 4 + 2 + rr][e];
                uq[i * 4 + 2 + rr][e] = tk[i * 4 + rr][e] - tk[i * 4 + 2 + rr][e];
            }
        }
    }

    // Stage 3 (over i -> p): o[4p+2q+r]
    float o[8][2];
#pragma unroll
    for (int qr = 0; qr < 4; ++qr) {
#pragma unroll
        for (int e = 0; e < 2; ++e) {
            o[0 + qr][e] = uq[qr][e] + uq[4 + qr][e];
            o[4 + qr][e] = uq[qr][e] - uq[4 + qr][e];
        }
    }

    // Output: out[b, c, 2d+p, 2h+q, 4*w2 + 2e + r]
    size_t out_cbase = ((size_t)(b * C_DIM + c)) * OUT_CH_STRIDE;
#pragma unroll
    for (int p = 0; p < 2; ++p) {
#pragma unroll
        for (int q = 0; q < 2; ++q) {
            size_t off = out_cbase
                       + (size_t)(2 * d + p) * (2 * H_DIM * 2 * W_DIM)
                       + (size_t)(2 * h + q) * (2 * W_DIM)
                       + (size_t)(4 * w2);
            f32x4 st;
            st.x = o[p * 4 + q * 2 + 0][0];  // e=0, r=0
            st.y = o[p * 4 + q * 2 + 1][0];  // e=0, r=1
            st.z = o[p * 4 + q * 2 + 0][1];  // e=1, r=0
            st.w = o[p * 4 + q * 2 + 1][1];  // e=1, r=1
            *reinterpret_cast<f32x4*>(out + off) = st;
        }
    }
}

extern "C" void kernel_launch(void* const* d_in, const int* in_sizes, int n_in,
                              void* d_out, int out_size, void* d_ws, size_t ws_size,
                              hipStream_t stream) {
    const float* x = (const float*)d_in[0];
    float* out = (float*)d_out;

    // B*C*D*H*W2 = 2*32*32*32*16 = 1,048,576 threads
    const int total = 2 * C_DIM * D_DIM * H_DIM * W2;
    const int block = 1024;
    const int grid = total / block;  // 1024
    iwt3d_kernel<<<grid, block, 0, stream>>>(x, out);
}

// Round 6
// 25.671 us; speedup vs baseline: 1.2163x; 1.0012x over previous
//
#include <hip/hip_runtime.h>
#include <hip/hip_bf16.h>

// 3D inverse Haar wavelet recombination.
// Input  x : (B=2, 8*C=256, D=32, H=32, W=32) fp32, band index = 4i+2j+k in
//            the high bits of the channel dim (c8 = band*32 + c).
// Output   : (B=2, C=32, 2D=64, 2H=64, 2W=64) fp32,
//            out[b,c,2d+p,2h+q,2w+r] = sum_{ijk} (-1)^(ip+jq+kr) x[b,(4i+2j+k)*C+c,d,h,w]
//
// R6: R5 structure (2 coarse w per thread — the exchange-free mapping with
// fully dense 16 B stores and dense 8 B loads), block 1024, PLUS:
// 2 iterations per thread (iter2 = other batch element, address = iter1 +
// constant), with iter2's 8 loads issued BEFORE iter1's butterfly so both
// iterations' reads are in flight together (2x MLP per wave, half the waves,
// prologue amortized over 12 KB instead of 6 KB).

typedef float f32x4 __attribute__((ext_vector_type(4)));

#define C_DIM   32
#define D_DIM   32
#define H_DIM   32
#define W_DIM   32
#define W2      (W_DIM / 2)                 // 16 w-pairs
#define SPATIAL (D_DIM * H_DIM * W_DIM)     // 32768
#define BAND_STRIDE (C_DIM * SPATIAL)       // 1048576 floats between bands
#define OUT_CH_STRIDE (8 * SPATIAL)         // 64*64*64 = 262144
#define IN_B_STRIDE  (8 * BAND_STRIDE)      // batch stride, input floats
#define OUT_B_STRIDE (C_DIM * OUT_CH_STRIDE)// batch stride, output floats

__device__ __forceinline__ void butterfly_and_store(const float v[8][2],
                                                    float* __restrict__ out,
                                                    size_t out_cbase,
                                                    int d, int h, int w2) {
    // Stage 1 (over k -> r): tk[4i+2j+r]
    float tk[8][2];
#pragma unroll
    for (int ij = 0; ij < 4; ++ij) {
#pragma unroll
        for (int e = 0; e < 2; ++e) {
            tk[ij * 2 + 0][e] = v[ij * 2 + 0][e] + v[ij * 2 + 1][e];
            tk[ij * 2 + 1][e] = v[ij * 2 + 0][e] - v[ij * 2 + 1][e];
        }
    }
    // Stage 2 (over j -> q): uq[4i+2q+r]
    float uq[8][2];
#pragma unroll
    for (int i = 0; i < 2; ++i) {
#pragma unroll
        for (int rr = 0; rr < 2; ++rr) {
#pragma unroll
            for (int e = 0; e < 2; ++e) {
                uq[i * 4 + 0 + rr][e] = tk[i * 4 + rr][e] + tk[i * 4 + 2 + rr][e];
                uq[i * 4 + 2 + rr][e] = tk[i * 4 + rr][e] - tk[i * 4 + 2 + rr][e];
            }
        }
    }
    // Stage 3 (over i -> p): o[4p+2q+r]
    float o[8][2];
#pragma unroll
    for (int qr = 0; qr < 4; ++qr) {
#pragma unroll
        for (int e = 0; e < 2; ++e) {
            o[0 + qr][e] = uq[qr][e] + uq[4 + qr][e];
            o[4 + qr][e] = uq[qr][e] - uq[4 + qr][e];
        }
    }
    // out[b, c, 2d+p, 2h+q, 4*w2 + 2e + r]
#pragma unroll
    for (int p = 0; p < 2; ++p) {
#pragma unroll
        for (int q = 0; q < 2; ++q) {
            size_t off = out_cbase
                       + (size_t)(2 * d + p) * (2 * H_DIM * 2 * W_DIM)
                       + (size_t)(2 * h + q) * (2 * W_DIM)
                       + (size_t)(4 * w2);
            f32x4 st;
            st.x = o[p * 4 + q * 2 + 0][0];
            st.y = o[p * 4 + q * 2 + 1][0];
            st.z = o[p * 4 + q * 2 + 0][1];
            st.w = o[p * 4 + q * 2 + 1][1];
            *reinterpret_cast<f32x4*>(out + off) = st;
        }
    }
}

__global__ __launch_bounds__(1024) void iwt3d_kernel(const float* __restrict__ x,
                                                     float* __restrict__ out) {
    int t = blockIdx.x * blockDim.x + threadIdx.x;
    // threads = C*D*H*W2 = 32*32*32*16 = 524,288; each does b=0 and b=1.

    int w2 = t & (W2 - 1);        int r = t >> 4;
    int h  = r & (H_DIM - 1);     r >>= 5;
    int d  = r & (D_DIM - 1);     r >>= 5;
    int c  = r & (C_DIM - 1);     // b handled by the 2 iterations

    size_t in_base = (size_t)c * SPATIAL
                   + (size_t)d * (H_DIM * W_DIM)
                   + (size_t)h * W_DIM
                   + (size_t)(w2 * 2);

    // Issue ALL 16 loads (both batch elements) before any compute.
    float v0[8][2], v1[8][2];
#pragma unroll
    for (int s = 0; s < 8; ++s) {
        float2 ld = *reinterpret_cast<const float2*>(x + in_base + (size_t)s * BAND_STRIDE);
        v0[s][0] = ld.x; v0[s][1] = ld.y;
    }
#pragma unroll
    for (int s = 0; s < 8; ++s) {
        float2 ld = *reinterpret_cast<const float2*>(
            x + in_base + IN_B_STRIDE + (size_t)s * BAND_STRIDE);
        v1[s][0] = ld.x; v1[s][1] = ld.y;
    }

    size_t out_cbase = (size_t)c * OUT_CH_STRIDE;
    butterfly_and_store(v0, out, out_cbase, d, h, w2);
    butterfly_and_store(v1, out, out_cbase + OUT_B_STRIDE, d, h, w2);
}

extern "C" void kernel_launch(void* const* d_in, const int* in_sizes, int n_in,
                              void* d_out, int out_size, void* d_ws, size_t ws_size,
                              hipStream_t stream) {
    const float* x = (const float*)d_in[0];
    float* out = (float*)d_out;

    // C*D*H*W2 = 524,288 threads, 2 batch elements each
    const int total = C_DIM * D_DIM * H_DIM * W2;
    const int block = 1024;
    const int grid = total / block;  // 512
    iwt3d_kernel<<<grid, block, 0, stream>>>(x, out);
}